// Round 1
// baseline (916.892 us; speedup 1.0000x reference)
//
#include <hip/hip_runtime.h>
#include <stdint.h>

typedef __bf16 bf16;
typedef __bf16 bf16x2 __attribute__((ext_vector_type(2)));
typedef __bf16 bf16x4 __attribute__((ext_vector_type(4)));
typedef __bf16 bf16x8 __attribute__((ext_vector_type(8)));
typedef float f32x16 __attribute__((ext_vector_type(16)));

#define SCALE 0.17677669529663687f   // 32^-0.5 (HEAD_DIM=32)
#define MFMA32(a, b, c) __builtin_amdgcn_mfma_f32_32x32x16_bf16((a), (b), (c), 0, 0, 0)

__device__ __forceinline__ f32x16 fzero16() {
  f32x16 v;
  #pragma unroll
  for (int i = 0; i < 16; ++i) v[i] = 0.f;
  return v;
}

__device__ __forceinline__ uint32_t pk2(float a, float b) {
  union { bf16x2 h; uint32_t u; } c;
  c.h[0] = (bf16)a; c.h[1] = (bf16)b;
  return c.u;
}

// Repack a 32x32 MFMA C/D fragment (value = M[(r&3)+8*(r>>2)+4*hk][lane&31]) into an
// A/B fragment of a following 32x32x16 MFMA where the source ROW dim becomes the k dim
// and the source COL dim stays on lane&31. HALF selects source rows [16*HALF,16*HALF+16).
// Output lane (lm,hk): frag[j] = M[16*HALF + 8*hk + j][lm], j=0..7.
// Derivation: j<4 from partner-half regs R+4*hk+{j}, j>=4 from other source half.
template<int HALF>
__device__ __forceinline__ bf16x8 repack_frag(f32x16 cc, int hk) {
  const int R = 8 * HALF;
  uint32_t pA0 = pk2(cc[R + 0], cc[R + 1]);   // own rows (hk_src = own half), k-low pair
  uint32_t pA1 = pk2(cc[R + 2], cc[R + 3]);
  uint32_t pB0 = pk2(cc[R + 4], cc[R + 5]);
  uint32_t pB1 = pk2(cc[R + 6], cc[R + 7]);
  uint32_t sA0 = __shfl_xor(pA0, 32, 64);
  uint32_t sA1 = __shfl_xor(pA1, 32, 64);
  uint32_t sB0 = __shfl_xor(pB0, 32, 64);
  uint32_t sB1 = __shfl_xor(pB1, 32, 64);
  union { uint32_t u[4]; bf16x8 v; } o;
  o.u[0] = hk ? sB0 : pA0;   // j=0,1  (from source lanes hk_src=0)
  o.u[1] = hk ? sB1 : pA1;   // j=2,3
  o.u[2] = hk ? pB0 : sA0;   // j=4,5  (from source lanes hk_src=1)
  o.u[3] = hk ? pB1 : sA1;   // j=6,7
  return o.v;
}

// ---------- precompute: M = SCALE * Wq Wk^T, stored as Mqk[b][a] = SCALE*sum_c Wk[b,c]*Wq[a,c]
__global__ __launch_bounds__(256) void k_mqk(const float* __restrict__ W, bf16* __restrict__ Mqk) {
  __shared__ float Wkt[32][65];
  __shared__ float Wqt[32][65];
  const int tb = (blockIdx.x >> 4) * 32;   // b tile
  const int ta = (blockIdx.x & 15) * 32;   // a tile
  const int tid = threadIdx.x;
  const int a_l = tid & 31, b_l = (tid >> 5) * 4;
  float acc[4] = {0.f, 0.f, 0.f, 0.f};
  for (int c0 = 0; c0 < 512; c0 += 64) {
    __syncthreads();
    for (int i = tid; i < 2048; i += 256) {
      int r = i >> 6, c = i & 63;
      Wkt[r][c] = W[(size_t)(tb + r) * 1536 + 512 + c0 + c];
      Wqt[r][c] = W[(size_t)(ta + r) * 1536 + c0 + c];
    }
    __syncthreads();
    for (int c = 0; c < 64; ++c) {
      float wq = Wqt[a_l][c];
      #pragma unroll
      for (int i = 0; i < 4; ++i) acc[i] += Wkt[b_l + i][c] * wq;
    }
  }
  #pragma unroll
  for (int i = 0; i < 4; ++i)
    Mqk[(size_t)(tb + b_l + i) * 512 + ta + a_l] = (bf16)(SCALE * acc[i]);
}

// ---------- precompute: WvT[cout][cin] = Wv[cin][cout]  (bf16)
__global__ __launch_bounds__(256) void k_wvt(const float* __restrict__ W, bf16* __restrict__ WvT) {
  const int cin = blockIdx.x;
  int n = threadIdx.x;
  WvT[(size_t)n * 512 + cin] = (bf16)W[(size_t)cin * 1536 + 1024 + n];
  n += 256;
  WvT[(size_t)n * 512 + cin] = (bf16)W[(size_t)cin * 1536 + 1024 + n];
}

// ---------- precompute: w2[b] = SCALE * sum_c Wk[b,c] * bq[c]
__global__ __launch_bounds__(256) void k_w2(const float* __restrict__ W, const float* __restrict__ bqkv,
                                            float* __restrict__ w2) {
  __shared__ float red[256];
  const int b = blockIdx.x, tid = threadIdx.x;
  float s = W[(size_t)b * 1536 + 512 + tid] * bqkv[tid]
          + W[(size_t)b * 1536 + 512 + 256 + tid] * bqkv[256 + tid];
  red[tid] = s;
  __syncthreads();
  for (int ofs = 128; ofs > 0; ofs >>= 1) {
    if (tid < ofs) red[tid] += red[tid + ofs];
    __syncthreads();
  }
  if (tid == 0) w2[b] = SCALE * red[0];
}

// ---------- fused per-window kernel ----------
// LDS = 50960 (Xs) + 9216 (Ps) + 12740 (Ss) + 2048 (ws2) + 256 (sbias) = 75220 B
// -> 2 workgroups/CU (needs VGPR <= 128, enforced by launch_bounds(512,4)).
struct __align__(16) SMem {
  bf16  Xs[49][520];   // staged X bf16; token rows >=49 handled via address clamp to row 48
  bf16  Ps[64][72];    // softmax probs (rows>=49 garbage-finite-or-NaN -> discarded O rows)
  float Ss[49][65];    // logits, k-split accumulated via ds_add_f32 atomics
  float ws2[512];      // staged w2
  float sbias[64];     // per-column bias term
};

__global__ __launch_bounds__(512, 4) void k_attn(
    const float* __restrict__ x, const float* __restrict__ bqkv,
    const bf16* __restrict__ Mqk, const bf16* __restrict__ WvT,
    const float* __restrict__ w2, float* __restrict__ out) {
  __shared__ SMem sm;
  const int tid = threadIdx.x;
  const int lane = tid & 63;
  const int lm = lane & 31, hk = lane >> 5;
  const int wave = tid >> 6;
  const int n_base = wave * 64;        // this wave's 64-wide channel slice
  const int wid = blockIdx.x;
  const float* xw = x + (size_t)wid * 25088;   // 49*512

  // ---- phase 0: stage X -> LDS bf16 (49 real rows only), stage w2, zero Ss
  for (int idx = tid; idx < 6272; idx += 512) {        // 49*512/4 float4s
    float4 f = ((const float4*)xw)[idx];
    int row = idx >> 7, c4 = (idx & 127) << 2;
    bf16x4 p;
    p[0] = (bf16)f.x; p[1] = (bf16)f.y; p[2] = (bf16)f.z; p[3] = (bf16)f.w;
    *(bf16x4*)&sm.Xs[row][c4] = p;
  }
  sm.ws2[tid] = w2[tid];
  for (int i = tid; i < 49 * 65; i += 512) ((float*)&sm.Ss[0][0])[i] = 0.f;
  __syncthreads();   // B0

  // Row pointers with clamp: token rows >=49 read row 48 (finite duplicate; only feeds
  // S rows >=49 (not stored), S cols >=49 (softmax-ignored), V rows >=49 (P=0 there)).
  const bf16* xs_lo = &sm.Xs[lm][0];
  const bf16* xs_hi = &sm.Xs[(32 + lm) < 49 ? (32 + lm) : 48][0];

  // ---- phase 1: C1 = (Mqk rows) x X^T  == T1^T fragments, kept in registers.
  // C1[b][i]: rows b = n_base+32*bb+layout, cols i = token = 32*T+lm.
  f32x16 c100 = fzero16(), c101 = fzero16(), c110 = fzero16(), c111 = fzero16();
  {
    const bf16* mq0 = Mqk + (size_t)(n_base + lm) * 512;
    const bf16* mq1 = Mqk + (size_t)(n_base + 32 + lm) * 512;
    #pragma unroll 4
    for (int k0 = 0; k0 < 512; k0 += 16) {
      const int ko = k0 + 8 * hk;
      bf16x8 fa0 = *(const bf16x8*)(mq0 + ko);
      bf16x8 fa1 = *(const bf16x8*)(mq1 + ko);
      bf16x8 fb0 = *(const bf16x8*)(xs_lo + ko);
      bf16x8 fb1 = *(const bf16x8*)(xs_hi + ko);
      c100 = MFMA32(fa0, fb0, c100); c101 = MFMA32(fa0, fb1, c101);
      c110 = MFMA32(fa1, fb0, c110); c111 = MFMA32(fa1, fb1, c111);
    }
  }

  // ---- repack C1 -> A-frags for S (k = this wave's 64 channels). aT{T}s{s}.
  bf16x8 aT0s0 = repack_frag<0>(c100, hk);
  bf16x8 aT0s1 = repack_frag<1>(c100, hk);
  bf16x8 aT0s2 = repack_frag<0>(c110, hk);
  bf16x8 aT0s3 = repack_frag<1>(c110, hk);
  bf16x8 aT1s0 = repack_frag<0>(c101, hk);
  bf16x8 aT1s1 = repack_frag<1>(c101, hk);
  bf16x8 aT1s2 = repack_frag<0>(c111, hk);
  bf16x8 aT1s3 = repack_frag<1>(c111, hk);

  // ---- phase 2: S-partial (64x64, k=64) + atomic accumulate into Ss
  {
    f32x16 s00 = fzero16(), s01 = fzero16(), s10 = fzero16(), s11 = fzero16();
    const bf16* xb0 = xs_lo + n_base;   // B[k=b_local][n=j]: j = token lm / 32+lm
    const bf16* xb1 = xs_hi + n_base;
    const int ho = 8 * hk;
    {
      bf16x8 fb0 = *(const bf16x8*)(xb0 + ho +  0);
      bf16x8 fb1 = *(const bf16x8*)(xb1 + ho +  0);
      s00 = MFMA32(aT0s0, fb0, s00); s01 = MFMA32(aT0s0, fb1, s01);
      s10 = MFMA32(aT1s0, fb0, s10); s11 = MFMA32(aT1s0, fb1, s11);
    }
    {
      bf16x8 fb0 = *(const bf16x8*)(xb0 + ho + 16);
      bf16x8 fb1 = *(const bf16x8*)(xb1 + ho + 16);
      s00 = MFMA32(aT0s1, fb0, s00); s01 = MFMA32(aT0s1, fb1, s01);
      s10 = MFMA32(aT1s1, fb0, s10); s11 = MFMA32(aT1s1, fb1, s11);
    }
    {
      bf16x8 fb0 = *(const bf16x8*)(xb0 + ho + 32);
      bf16x8 fb1 = *(const bf16x8*)(xb1 + ho + 32);
      s00 = MFMA32(aT0s2, fb0, s00); s01 = MFMA32(aT0s2, fb1, s01);
      s10 = MFMA32(aT1s2, fb0, s10); s11 = MFMA32(aT1s2, fb1, s11);
    }
    {
      bf16x8 fb0 = *(const bf16x8*)(xb0 + ho + 48);
      bf16x8 fb1 = *(const bf16x8*)(xb1 + ho + 48);
      s00 = MFMA32(aT0s3, fb0, s00); s01 = MFMA32(aT0s3, fb1, s01);
      s10 = MFMA32(aT1s3, fb0, s10); s11 = MFMA32(aT1s3, fb1, s11);
    }
    #pragma unroll
    for (int r = 0; r < 16; ++r) {
      const int row = (r & 3) + 8 * (r >> 2) + 4 * hk;
      if (row < 49) {
        atomicAdd(&sm.Ss[row][lm],      s00[r]);
        atomicAdd(&sm.Ss[row][32 + lm], s01[r]);
      }
      const int row1 = 32 + row;
      if (row1 < 49) {
        atomicAdd(&sm.Ss[row1][lm],      s10[r]);
        atomicAdd(&sm.Ss[row1][32 + lm], s11[r]);
      }
    }
  }

  // ---- sbias_j = X_j . w2 (all 512 threads; 8 lanes per row)
  {
    const int brow = tid >> 3, bsub = tid & 7;
    if (brow < 49) {
      const bf16* xr = &sm.Xs[brow][bsub * 64];
      const float* wr = &sm.ws2[bsub * 64];
      float s = 0.f;
      #pragma unroll
      for (int t = 0; t < 8; ++t) {
        bf16x8 xv = *(const bf16x8*)(xr + 8 * t);
        #pragma unroll
        for (int e = 0; e < 8; ++e) s += (float)xv[e] * wr[8 * t + e];
      }
      s += __shfl_xor(s, 1, 64);
      s += __shfl_xor(s, 2, 64);
      s += __shfl_xor(s, 4, 64);
      if (bsub == 0) sm.sbias[brow] = s;
    }
  }

  // ---- phase 4: V = X * Wv + bv, kept in registers (C-frag col = V channel on lane&31)
  f32x16 v00 = fzero16(), v01 = fzero16(), v10 = fzero16(), v11 = fzero16();
  {
    const bf16* wv0 = WvT + (size_t)(n_base + lm) * 512;
    const bf16* wv1 = WvT + (size_t)(n_base + 32 + lm) * 512;
    #pragma unroll 4
    for (int k0 = 0; k0 < 512; k0 += 16) {
      const int ko = k0 + 8 * hk;
      bf16x8 fa0 = *(const bf16x8*)(xs_lo + ko);
      bf16x8 fa1 = *(const bf16x8*)(xs_hi + ko);
      bf16x8 fb0 = *(const bf16x8*)(wv0 + ko);
      bf16x8 fb1 = *(const bf16x8*)(wv1 + ko);
      v00 = MFMA32(fa0, fb0, v00); v01 = MFMA32(fa0, fb1, v01);
      v10 = MFMA32(fa1, fb0, v10); v11 = MFMA32(fa1, fb1, v11);
    }
    const float bv0 = bqkv[1024 + n_base + lm];
    const float bv1 = bqkv[1024 + n_base + 32 + lm];
    #pragma unroll
    for (int r = 0; r < 16; ++r) {
      v00[r] += bv0; v01[r] += bv1; v10[r] += bv0; v11[r] += bv1;
    }
  }
  // repack V -> B-frags for O: bV{cb}{s}, k = tokens 16s..16s+16
  bf16x8 bV00 = repack_frag<0>(v00, hk);   // cb=0, tokens  0-15
  bf16x8 bV01 = repack_frag<1>(v00, hk);   // cb=0, tokens 16-31
  bf16x8 bV02 = repack_frag<0>(v10, hk);   // cb=0, tokens 32-47
  bf16x8 bV03 = repack_frag<1>(v10, hk);   // cb=0, tokens 48-63
  bf16x8 bV10 = repack_frag<0>(v01, hk);   // cb=1, tokens  0-15
  bf16x8 bV11 = repack_frag<1>(v01, hk);
  bf16x8 bV12 = repack_frag<0>(v11, hk);
  bf16x8 bV13 = repack_frag<1>(v11, hk);

  __syncthreads();   // B1 — all S atomics landed

  // ---- phase 3: wave-parallel masked softmax: 8 lanes per row, rows 0..48
  {
    const int srow = tid >> 3, sub = tid & 7;
    if (srow < 49) {
      float v[8];
      #pragma unroll
      for (int t = 0; t < 8; ++t) {
        const int col = sub + 8 * t;
        v[t] = (col < 49) ? (sm.Ss[srow][col] + sm.sbias[col]) : -1e30f;
      }
      float m = v[0];
      #pragma unroll
      for (int t = 1; t < 8; ++t) m = fmaxf(m, v[t]);
      m = fmaxf(m, __shfl_xor(m, 1, 64));
      m = fmaxf(m, __shfl_xor(m, 2, 64));
      m = fmaxf(m, __shfl_xor(m, 4, 64));
      float e[8]; float ssum = 0.f;
      #pragma unroll
      for (int t = 0; t < 8; ++t) {
        const int col = sub + 8 * t;
        e[t] = (col < 49) ? __expf(v[t] - m) : 0.f;
        ssum += e[t];
      }
      ssum += __shfl_xor(ssum, 1, 64);
      ssum += __shfl_xor(ssum, 2, 64);
      ssum += __shfl_xor(ssum, 4, 64);
      const float inv = 1.f / ssum;
      #pragma unroll
      for (int t = 0; t < 8; ++t)
        sm.Ps[srow][sub + 8 * t] = (bf16)(e[t] * inv);
    }
  }
  __syncthreads();   // B2 — Ps complete

  // ---- phase 5: O = P * V (A from Ps LDS, B from registers)
  f32x16 o00 = fzero16(), o01 = fzero16(), o10 = fzero16(), o11 = fzero16();
  {
    const bf16* p0 = &sm.Ps[lm][8 * hk];
    const bf16* p1 = &sm.Ps[32 + lm][8 * hk];
    bf16x8 fa0, fa1;
    fa0 = *(const bf16x8*)(p0 +  0); fa1 = *(const bf16x8*)(p1 +  0);
    o00 = MFMA32(fa0, bV00, o00); o01 = MFMA32(fa0, bV10, o01);
    o10 = MFMA32(fa1, bV00, o10); o11 = MFMA32(fa1, bV10, o11);
    fa0 = *(const bf16x8*)(p0 + 16); fa1 = *(const bf16x8*)(p1 + 16);
    o00 = MFMA32(fa0, bV01, o00); o01 = MFMA32(fa0, bV11, o01);
    o10 = MFMA32(fa1, bV01, o10); o11 = MFMA32(fa1, bV11, o11);
    fa0 = *(const bf16x8*)(p0 + 32); fa1 = *(const bf16x8*)(p1 + 32);
    o00 = MFMA32(fa0, bV02, o00); o01 = MFMA32(fa0, bV12, o01);
    o10 = MFMA32(fa1, bV02, o10); o11 = MFMA32(fa1, bV12, o11);
    fa0 = *(const bf16x8*)(p0 + 48); fa1 = *(const bf16x8*)(p1 + 48);
    o00 = MFMA32(fa0, bV03, o00); o01 = MFMA32(fa0, bV13, o01);
    o10 = MFMA32(fa1, bV03, o10); o11 = MFMA32(fa1, bV13, o11);
  }
  // ---- store rows < 49
  float* ow = out + (size_t)wid * 25088;
  const int c0_ = n_base + lm, c1_ = n_base + 32 + lm;
  #pragma unroll
  for (int r = 0; r < 16; ++r) {
    const int row = (r & 3) + 8 * (r >> 2) + 4 * hk;
    if (row < 49) {
      ow[row * 512 + c0_] = o00[r];
      ow[row * 512 + c1_] = o01[r];
    }
    const int row1 = 32 + row;
    if (row1 < 49) {
      ow[row1 * 512 + c0_] = o10[r];
      ow[row1 * 512 + c1_] = o11[r];
    }
  }
}

extern "C" void kernel_launch(void* const* d_in, const int* in_sizes, int n_in,
                              void* d_out, int out_size, void* d_ws, size_t ws_size,
                              hipStream_t stream) {
  const float* x    = (const float*)d_in[0];
  // d_in[1] (x_all) is unused by the reference
  const float* W    = (const float*)d_in[2];
  const float* bqkv = (const float*)d_in[3];
  float* out = (float*)d_out;

  bf16*  Mqk = (bf16*)d_ws;                                    // 512*512*2 = 512 KB
  bf16*  WvT = (bf16*)((char*)d_ws + 512 * 512 * 2);           // 512 KB
  float* w2  = (float*)((char*)d_ws + 2 * 512 * 512 * 2);      // 2 KB

  k_mqk<<<256, 256, 0, stream>>>(W, Mqk);
  k_wvt<<<512, 256, 0, stream>>>(W, WvT);
  k_w2 <<<512, 256, 0, stream>>>(W, bqkv, w2);
  k_attn<<<2048, 512, 0, stream>>>(x, bqkv, Mqk, WvT, w2, out);
}

// Round 2
// 773.329 us; speedup vs baseline: 1.1856x; 1.1856x over previous
//
#include <hip/hip_runtime.h>
#include <stdint.h>

typedef __bf16 bf16;
typedef __bf16 bf16x4 __attribute__((ext_vector_type(4)));
typedef __bf16 bf16x8 __attribute__((ext_vector_type(8)));
typedef float f32x16 __attribute__((ext_vector_type(16)));

#define SCALE 0.17677669529663687f   // 32^-0.5 (HEAD_DIM=32)
#define MFMA32(a, b, c) __builtin_amdgcn_mfma_f32_32x32x16_bf16((a), (b), (c), 0, 0, 0)

__device__ __forceinline__ f32x16 fzero16() {
  f32x16 v;
  #pragma unroll
  for (int i = 0; i < 16; ++i) v[i] = 0.f;
  return v;
}

// ---------- precompute: M = SCALE * Wq Wk^T, stored as Mqk[b][a] = SCALE*sum_c Wk[b,c]*Wq[a,c]
__global__ __launch_bounds__(256) void k_mqk(const float* __restrict__ W, bf16* __restrict__ Mqk) {
  __shared__ float Wkt[32][65];
  __shared__ float Wqt[32][65];
  const int tb = (blockIdx.x >> 4) * 32;   // b tile
  const int ta = (blockIdx.x & 15) * 32;   // a tile
  const int tid = threadIdx.x;
  const int a_l = tid & 31, b_l = (tid >> 5) * 4;
  float acc[4] = {0.f, 0.f, 0.f, 0.f};
  for (int c0 = 0; c0 < 512; c0 += 64) {
    __syncthreads();
    for (int i = tid; i < 2048; i += 256) {
      int r = i >> 6, c = i & 63;
      Wkt[r][c] = W[(size_t)(tb + r) * 1536 + 512 + c0 + c];
      Wqt[r][c] = W[(size_t)(ta + r) * 1536 + c0 + c];
    }
    __syncthreads();
    for (int c = 0; c < 64; ++c) {
      float wq = Wqt[a_l][c];
      #pragma unroll
      for (int i = 0; i < 4; ++i) acc[i] += Wkt[b_l + i][c] * wq;
    }
  }
  #pragma unroll
  for (int i = 0; i < 4; ++i)
    Mqk[(size_t)(tb + b_l + i) * 512 + ta + a_l] = (bf16)(SCALE * acc[i]);
}

// ---------- precompute: WvT[cout][cin] = Wv[cin][cout]  (bf16), LDS-tiled coalesced transpose
__global__ __launch_bounds__(256) void k_wvt(const float* __restrict__ W, bf16* __restrict__ WvT) {
  __shared__ float Wt[64][68];
  const int cin0  = (blockIdx.x & 7) * 64;
  const int cout0 = (blockIdx.x >> 3) * 64;
  const int tid = threadIdx.x;
  {
    const int r = tid >> 2, cq = (tid & 3) * 16;
    #pragma unroll
    for (int cc = 0; cc < 4; ++cc) {
      float4 f = *(const float4*)&W[(size_t)(cin0 + r) * 1536 + 1024 + cout0 + cq + 4 * cc];
      Wt[r][cq + 4 * cc + 0] = f.x;
      Wt[r][cq + 4 * cc + 1] = f.y;
      Wt[r][cq + 4 * cc + 2] = f.z;
      Wt[r][cq + 4 * cc + 3] = f.w;
    }
  }
  __syncthreads();
  {
    const int co = tid >> 2, seg = (tid & 3) * 16;
    bf16x8 p0, p1;
    #pragma unroll
    for (int e = 0; e < 8; ++e) p0[e] = (bf16)Wt[seg + e][co];
    #pragma unroll
    for (int e = 0; e < 8; ++e) p1[e] = (bf16)Wt[seg + 8 + e][co];
    *(bf16x8*)&WvT[(size_t)(cout0 + co) * 512 + cin0 + seg]     = p0;
    *(bf16x8*)&WvT[(size_t)(cout0 + co) * 512 + cin0 + seg + 8] = p1;
  }
}

// ---------- precompute: w2[b] = SCALE * sum_c Wk[b,c] * bq[c]
__global__ __launch_bounds__(256) void k_w2(const float* __restrict__ W, const float* __restrict__ bqkv,
                                            float* __restrict__ w2) {
  __shared__ float red[256];
  const int b = blockIdx.x, tid = threadIdx.x;
  float s = W[(size_t)b * 1536 + 512 + tid] * bqkv[tid]
          + W[(size_t)b * 1536 + 512 + 256 + tid] * bqkv[256 + tid];
  red[tid] = s;
  __syncthreads();
  for (int ofs = 128; ofs > 0; ofs >>= 1) {
    if (tid < ofs) red[tid] += red[tid + ofs];
    __syncthreads();
  }
  if (tid == 0) w2[b] = SCALE * red[0];
}

// ---------- fused per-window kernel ----------
// LDS total = 66560 + 73728 + 13520 + 9216 + 256 = 163280 <= 163840 (gfx950)
struct SMem {
  bf16 Xs[64][520];                                   // X window, bf16, rows>=49 zero; +8 pad for 16B rows
  union { bf16 T1s[64][520]; bf16 Vt[512][72]; } u;   // T1 = X*M (phase 1-2), then V^T (phase 4-5)
  float Ss[52][65];                                   // logits
  bf16 Ps[64][72];                                    // softmax probs (rows>=49 garbage, discarded)
  float sbias[64];                                    // s_j bias term
};

__global__ __launch_bounds__(512, 2) void k_attn(
    const float* __restrict__ x, const float* __restrict__ bqkv,
    const bf16* __restrict__ Mqk, const bf16* __restrict__ WvT,
    const float* __restrict__ w2, float* __restrict__ out) {
  __shared__ SMem sm;
  const int tid = threadIdx.x;
  const int wave = tid >> 6, lane = tid & 63;
  const int lm = lane & 31, hk = lane >> 5;   // 32x32x16 frag: m/n = lane&31, k-group = lane>>5
  const int wid = blockIdx.x;
  const float* xw = x + (size_t)wid * 25088;  // 49*512

  // ---- phase 0: stage X -> LDS bf16, zero pad rows 49..63
  for (int idx = tid; idx < 6272; idx += 512) {       // 49*512/4 float4s
    float4 f = ((const float4*)xw)[idx];
    int row = idx >> 7, c4 = (idx & 127) << 2;
    bf16x4 p;
    p[0] = (bf16)f.x; p[1] = (bf16)f.y; p[2] = (bf16)f.z; p[3] = (bf16)f.w;
    *(bf16x4*)&sm.Xs[row][c4] = p;
  }
  for (int idx = tid; idx < 15 * 130; idx += 512) {
    int r = 49 + idx / 130, c = (idx % 130) * 4;
    bf16x4 z; z[0] = (bf16)0.f; z[1] = (bf16)0.f; z[2] = (bf16)0.f; z[3] = (bf16)0.f;
    *(bf16x4*)&sm.Xs[r][c] = z;
  }
  __syncthreads();

  // ---- phase 1+4 merged: T1 = X*M and V = X*Wv in ONE k-loop (shared A-fragments,
  //      8 independent accumulator chains -> 2x MFMA per L2 load, half the LDS A-traffic).
  //      V accumulators stay live in AGPRs until after the phase-2 barrier.
  f32x16 v00, v01, v10, v11;   // V accs (dumped to Vt after phase 2)
  {
    const int n_base = wave * 64;
    f32x16 t00 = fzero16(), t01 = fzero16(), t10 = fzero16(), t11 = fzero16();
    v00 = fzero16(); v01 = fzero16(); v10 = fzero16(); v11 = fzero16();
    const bf16* a0p = &sm.Xs[lm][0];
    const bf16* a1p = &sm.Xs[32 + lm][0];
    const bf16* b0g = Mqk + (size_t)(n_base + lm) * 512;
    const bf16* b1g = Mqk + (size_t)(n_base + 32 + lm) * 512;
    const bf16* c0g = WvT + (size_t)(n_base + lm) * 512;
    const bf16* c1g = WvT + (size_t)(n_base + 32 + lm) * 512;
    #pragma unroll 2
    for (int k0 = 0; k0 < 512; k0 += 16) {
      const int ko = k0 + 8 * hk;
      bf16x8 fa0 = *(const bf16x8*)(a0p + ko);
      bf16x8 fa1 = *(const bf16x8*)(a1p + ko);
      bf16x8 fb0 = *(const bf16x8*)(b0g + ko);
      bf16x8 fb1 = *(const bf16x8*)(b1g + ko);
      bf16x8 fc0 = *(const bf16x8*)(c0g + ko);
      bf16x8 fc1 = *(const bf16x8*)(c1g + ko);
      t00 = MFMA32(fa0, fb0, t00); t01 = MFMA32(fa0, fb1, t01);
      t10 = MFMA32(fa1, fb0, t10); t11 = MFMA32(fa1, fb1, t11);
      v00 = MFMA32(fa0, fc0, v00); v01 = MFMA32(fa0, fc1, v01);
      v10 = MFMA32(fa1, fc0, v10); v11 = MFMA32(fa1, fc1, v11);
    }
    #pragma unroll
    for (int reg = 0; reg < 16; ++reg) {
      const int row = (reg & 3) + 8 * (reg >> 2) + 4 * hk;  // C/D layout [m74/m101]
      sm.u.T1s[row][n_base + lm]           = (bf16)t00[reg];
      sm.u.T1s[row][n_base + 32 + lm]      = (bf16)t01[reg];
      sm.u.T1s[32 + row][n_base + lm]      = (bf16)t10[reg];
      sm.u.T1s[32 + row][n_base + 32 + lm] = (bf16)t11[reg];
    }
  }
  __syncthreads();

  // ---- phase 2: waves 0-3: S = T1 * X^T (64x64, k=512); waves 4-7: sbias_j = X_j . w2
  if (wave < 4) {
    const int r = wave & 1, c = wave >> 1;
    f32x16 accS = fzero16();
    const bf16* ap = &sm.u.T1s[32 * r + lm][0];
    const bf16* bp = &sm.Xs[32 * c + lm][0];   // B[k=b][n=j] = X[j][b]: k-contiguous along Xs row
    #pragma unroll 4
    for (int k0 = 0; k0 < 512; k0 += 16) {
      const int ko = k0 + 8 * hk;
      bf16x8 fa = *(const bf16x8*)(ap + ko);
      bf16x8 fb = *(const bf16x8*)(bp + ko);
      accS = MFMA32(fa, fb, accS);
    }
    #pragma unroll
    for (int reg = 0; reg < 16; ++reg) {
      const int row = 32 * r + (reg & 3) + 8 * (reg >> 2) + 4 * hk;
      if (row < 52) sm.Ss[row][32 * c + lm] = accS[reg];
    }
  } else {
    const int t2 = tid - 256;
    const int j = t2 >> 2, part = t2 & 3;
    float s = 0.f;
    for (int cc = part * 128; cc < part * 128 + 128; ++cc)
      s += (float)sm.Xs[j][cc] * w2[cc];
    s += __shfl_xor(s, 1);
    s += __shfl_xor(s, 2);
    if (part == 0) sm.sbias[j] = s;
  }
  __syncthreads();

  // ---- phase 3: wave-parallel masked softmax: 8 lanes per row, rows 0..48
  {
    const int srow = tid >> 3, sub = tid & 7;
    if (srow < 49) {
      float v[8];
      #pragma unroll
      for (int t = 0; t < 8; ++t) {
        const int col = sub + 8 * t;
        v[t] = (col < 49) ? (sm.Ss[srow][col] + sm.sbias[col]) : -1e30f;
      }
      float m = v[0];
      #pragma unroll
      for (int t = 1; t < 8; ++t) m = fmaxf(m, v[t]);
      m = fmaxf(m, __shfl_xor(m, 1, 64));
      m = fmaxf(m, __shfl_xor(m, 2, 64));
      m = fmaxf(m, __shfl_xor(m, 4, 64));
      float e[8]; float ssum = 0.f;
      #pragma unroll
      for (int t = 0; t < 8; ++t) {
        const int col = sub + 8 * t;
        e[t] = (col < 49) ? __expf(v[t] - m) : 0.f;
        ssum += e[t];
      }
      ssum += __shfl_xor(ssum, 1, 64);
      ssum += __shfl_xor(ssum, 2, 64);
      ssum += __shfl_xor(ssum, 4, 64);
      const float inv = 1.f / ssum;
      #pragma unroll
      for (int t = 0; t < 8; ++t)
        sm.Ps[srow][sub + 8 * t] = (bf16)(e[t] * inv);
    }
  }

  // ---- phase 4 (dump): V accs + bias -> Vt[chan][token]  (T1s reads finished at barrier above)
  {
    const int n_base = wave * 64;
    const float bv0 = bqkv[1024 + n_base + lm];
    const float bv1 = bqkv[1024 + n_base + 32 + lm];
    #pragma unroll
    for (int g = 0; g < 4; ++g) {
      const int t0 = 8 * g + 4 * hk;   // 4 consecutive token rows per reg-group
      bf16x4 p0, p1, p2, p3;
      #pragma unroll
      for (int j = 0; j < 4; ++j) {
        p0[j] = (bf16)(v00[4 * g + j] + bv0);
        p1[j] = (bf16)(v01[4 * g + j] + bv1);
        p2[j] = (bf16)(v10[4 * g + j] + bv0);
        p3[j] = (bf16)(v11[4 * g + j] + bv1);
      }
      *(bf16x4*)&sm.u.Vt[n_base + lm][t0]           = p0;
      *(bf16x4*)&sm.u.Vt[n_base + 32 + lm][t0]      = p1;
      *(bf16x4*)&sm.u.Vt[n_base + lm][32 + t0]      = p2;
      *(bf16x4*)&sm.u.Vt[n_base + 32 + lm][32 + t0] = p3;
    }
  }
  __syncthreads();

  // ---- phase 5: O = P * V (64x512, k=64), store f32 rows < 49
  {
    const int n_base = wave * 64;
    f32x16 a00 = fzero16(), a01 = fzero16(), a10 = fzero16(), a11 = fzero16();
    #pragma unroll
    for (int k0 = 0; k0 < 64; k0 += 16) {
      const int ko = k0 + 8 * hk;
      bf16x8 fa0 = *(const bf16x8*)&sm.Ps[lm][ko];
      bf16x8 fa1 = *(const bf16x8*)&sm.Ps[32 + lm][ko];
      bf16x8 fb0 = *(const bf16x8*)&sm.u.Vt[n_base + lm][ko];
      bf16x8 fb1 = *(const bf16x8*)&sm.u.Vt[n_base + 32 + lm][ko];
      a00 = MFMA32(fa0, fb0, a00); a01 = MFMA32(fa0, fb1, a01);
      a10 = MFMA32(fa1, fb0, a10); a11 = MFMA32(fa1, fb1, a11);
    }
    float* ow = out + (size_t)wid * 25088;
    const int c0_ = n_base + lm, c1_ = n_base + 32 + lm;
    #pragma unroll
    for (int reg = 0; reg < 16; ++reg) {
      const int row = (reg & 3) + 8 * (reg >> 2) + 4 * hk;
      if (row < 49) {
        ow[row * 512 + c0_] = a00[reg];
        ow[row * 512 + c1_] = a01[reg];
      }
      const int row1 = 32 + row;
      if (row1 < 49) {
        ow[row1 * 512 + c0_] = a10[reg];
        ow[row1 * 512 + c1_] = a11[reg];
      }
    }
  }
}

extern "C" void kernel_launch(void* const* d_in, const int* in_sizes, int n_in,
                              void* d_out, int out_size, void* d_ws, size_t ws_size,
                              hipStream_t stream) {
  const float* x    = (const float*)d_in[0];
  // d_in[1] (x_all) is unused by the reference
  const float* W    = (const float*)d_in[2];
  const float* bqkv = (const float*)d_in[3];
  float* out = (float*)d_out;

  bf16*  Mqk = (bf16*)d_ws;                                    // 512*512*2 = 512 KB
  bf16*  WvT = (bf16*)((char*)d_ws + 512 * 512 * 2);           // 512 KB
  float* w2  = (float*)((char*)d_ws + 2 * 512 * 512 * 2);      // 2 KB

  k_mqk<<<256, 256, 0, stream>>>(W, Mqk);
  k_wvt<<<64, 256, 0, stream>>>(W, WvT);
  k_w2 <<<512, 256, 0, stream>>>(W, bqkv, w2);
  k_attn<<<2048, 512, 0, stream>>>(x, bqkv, Mqk, WvT, w2, out);
}

// Round 4
// 636.705 us; speedup vs baseline: 1.4401x; 1.2146x over previous
//
#include <hip/hip_runtime.h>
#include <stdint.h>

typedef __bf16 bf16;
typedef __bf16 bf16x4 __attribute__((ext_vector_type(4)));
typedef __bf16 bf16x8 __attribute__((ext_vector_type(8)));
typedef float f32x16 __attribute__((ext_vector_type(16)));

#define SCALE 0.17677669529663687f   // 32^-0.5 (HEAD_DIM=32)
#define MFMA32(a, b, c) __builtin_amdgcn_mfma_f32_32x32x16_bf16((a), (b), (c), 0, 0, 0)

__device__ __forceinline__ f32x16 fzero16() {
  f32x16 v;
  #pragma unroll
  for (int i = 0; i < 16; ++i) v[i] = 0.f;
  return v;
}

// Fragment-ordered weight layout ("F-layout"):
//   element (row n, col k) of the logical [512][512] B^T matrix lives at
//   flat = ((n>>5)*32 + (k>>4))*512 + (((k>>3)&1)*32 + (n&31))*8 + (k&7)
// so that a wave's bf16x8 B-fragment load for tile (nb, kc) is
//   *(bf16x8*)(W + (nb*32+kc)*512 + lane*8)  -- 1 KB fully contiguous per instr.

// ---------- precompute: M = SCALE * Wq Wk^T in F-layout
__global__ __launch_bounds__(256) void k_mqk(const float* __restrict__ W, bf16* __restrict__ MqkF) {
  __shared__ float Wkt[32][65];
  __shared__ float Wqt[32][65];
  const int tb = (blockIdx.x >> 4) * 32;   // n tile (Wk rows)
  const int ta = (blockIdx.x & 15) * 32;   // k tile (Wq rows)
  const int tid = threadIdx.x;
  const int a_l = tid & 31, b_l = (tid >> 5) * 4;
  float acc[4] = {0.f, 0.f, 0.f, 0.f};
  for (int c0 = 0; c0 < 512; c0 += 64) {
    __syncthreads();
    for (int i = tid; i < 2048; i += 256) {
      int r = i >> 6, c = i & 63;
      Wkt[r][c] = W[(size_t)(tb + r) * 1536 + 512 + c0 + c];
      Wqt[r][c] = W[(size_t)(ta + r) * 1536 + c0 + c];
    }
    __syncthreads();
    for (int c = 0; c < 64; ++c) {
      float wq = Wqt[a_l][c];
      #pragma unroll
      for (int i = 0; i < 4; ++i) acc[i] += Wkt[b_l + i][c] * wq;
    }
  }
  const int col = ta + a_l;                         // k index
  const int kc = col >> 4, hkc = (col >> 3) & 1, jc = col & 7;
  #pragma unroll
  for (int i = 0; i < 4; ++i) {
    const int row = tb + b_l + i;                   // n index
    MqkF[(size_t)(((row >> 5) * 32 + kc) * 64 + hkc * 32 + (row & 31)) * 8 + jc]
        = (bf16)(SCALE * acc[i]);
  }
}

// ---------- precompute: Wv^T in F-layout (row n = cout, col k = cin)
__global__ __launch_bounds__(256) void k_wvt(const float* __restrict__ W, bf16* __restrict__ WvTF) {
  __shared__ float Wt[64][68];
  const int cin0  = (blockIdx.x & 7) * 64;
  const int cout0 = (blockIdx.x >> 3) * 64;
  const int tid = threadIdx.x;
  {
    const int r = tid >> 2, cq = (tid & 3) * 16;
    #pragma unroll
    for (int cc = 0; cc < 4; ++cc) {
      float4 f = *(const float4*)&W[(size_t)(cin0 + r) * 1536 + 1024 + cout0 + cq + 4 * cc];
      Wt[r][cq + 4 * cc + 0] = f.x;
      Wt[r][cq + 4 * cc + 1] = f.y;
      Wt[r][cq + 4 * cc + 2] = f.z;
      Wt[r][cq + 4 * cc + 3] = f.w;
    }
  }
  __syncthreads();
  {
    const int co = tid >> 2, seg = (tid & 3) * 16;
    const int row = cout0 + co;                 // n = cout
    bf16x8 p0, p1;
    #pragma unroll
    for (int e = 0; e < 8; ++e) p0[e] = (bf16)Wt[seg + e][co];       // k = cin0+seg+e   (hk=0)
    #pragma unroll
    for (int e = 0; e < 8; ++e) p1[e] = (bf16)Wt[seg + 8 + e][co];   // k = cin0+seg+8+e (hk=1)
    const size_t base = (size_t)(((row >> 5) * 32 + ((cin0 + seg) >> 4))) * 512
                      + (size_t)(row & 31) * 8;
    *(bf16x8*)&WvTF[base]       = p0;
    *(bf16x8*)&WvTF[base + 256] = p1;           // +32*8 (hk=1 half)
  }
}

// ---------- precompute: w2[b] = SCALE * sum_c Wk[b,c] * bq[c]
__global__ __launch_bounds__(256) void k_w2(const float* __restrict__ W, const float* __restrict__ bqkv,
                                            float* __restrict__ w2) {
  __shared__ float red[256];
  const int b = blockIdx.x, tid = threadIdx.x;
  float s = W[(size_t)b * 1536 + 512 + tid] * bqkv[tid]
          + W[(size_t)b * 1536 + 512 + 256 + tid] * bqkv[256 + tid];
  red[tid] = s;
  __syncthreads();
  for (int ofs = 128; ofs > 0; ofs >>= 1) {
    if (tid < ofs) red[tid] += red[tid + ofs];
    __syncthreads();
  }
  if (tid == 0) w2[b] = SCALE * red[0];
}

// ---------- fused per-window kernel ----------
// LDS total = 66560 + 73728 + 13520 + 9216 + 256 = 163280 <= 163840 (gfx950)
struct SMem {
  bf16 Xs[64][520];                                   // X window, bf16, rows>=49 zero; +8 pad for 16B rows
  union { bf16 T1s[64][520]; bf16 Vt[512][72]; } u;   // T1 = X*M (phase 1-2), then V^T (phase 4-5)
  float Ss[52][65];                                   // logits
  bf16 Ps[64][72];                                    // softmax probs; bytes [0,2048) host ws2 until phase 3
  float sbias[64];                                    // s_j bias term
};

__global__ __launch_bounds__(512, 2) void k_attn(
    const float* __restrict__ x, const float* __restrict__ bqkv,
    const bf16* __restrict__ MqkF, const bf16* __restrict__ WvTF,
    const float* __restrict__ w2, float* __restrict__ out) {
  __shared__ SMem sm;
  float* const ws2 = (float*)&sm.Ps[0][0];    // overlay: live phase 0..2, Ps written in phase 3
  const int tid = threadIdx.x;
  const int wave = tid >> 6, lane = tid & 63;
  const int lm = lane & 31, hk = lane >> 5;   // 32x32x16 frag: m/n = lane&31, k-group = lane>>5
  const int wid = blockIdx.x;
  const float* xw = x + (size_t)wid * 25088;  // 49*512

  // ---- phase 0: stage X -> LDS bf16, zero pad rows 49..63, stash w2
  for (int idx = tid; idx < 6272; idx += 512) {       // 49*512/4 float4s
    float4 f = ((const float4*)xw)[idx];
    int row = idx >> 7, c4 = (idx & 127) << 2;
    bf16x4 p;
    p[0] = (bf16)f.x; p[1] = (bf16)f.y; p[2] = (bf16)f.z; p[3] = (bf16)f.w;
    *(bf16x4*)&sm.Xs[row][c4] = p;
  }
  for (int idx = tid; idx < 15 * 130; idx += 512) {
    int r = 49 + idx / 130, c = (idx % 130) * 4;
    bf16x4 z; z[0] = (bf16)0.f; z[1] = (bf16)0.f; z[2] = (bf16)0.f; z[3] = (bf16)0.f;
    *(bf16x4*)&sm.Xs[r][c] = z;
  }
  ws2[tid] = w2[tid];

  // ---- weight prefetch (kc=0 tiles) issued BEFORE the staging barrier: F-layout,
  //      each instr reads 1KB contiguous (64 lanes x 16B).
  const size_t lo = (size_t)lane * 8;
  const bf16* mq0 = MqkF + (size_t)(2 * wave)     * 16384 + lo;   // 32*512 elems per row-block
  const bf16* mq1 = MqkF + (size_t)(2 * wave + 1) * 16384 + lo;
  const bf16* vv0 = WvTF + (size_t)(2 * wave)     * 16384 + lo;
  const bf16* vv1 = WvTF + (size_t)(2 * wave + 1) * 16384 + lo;
  bf16x8 pb0 = *(const bf16x8*)(mq0);
  bf16x8 pb1 = *(const bf16x8*)(mq1);
  bf16x8 pc0 = *(const bf16x8*)(vv0);
  bf16x8 pc1 = *(const bf16x8*)(vv1);
  __syncthreads();   // B0

  // ---- phase 1+4 merged: T1 = X*M and V = X*Wv in ONE k-loop, depth-1 weight prefetch.
  f32x16 v00, v01, v10, v11;   // V accs (dumped to Vt after phase 2)
  {
    const int n_base = wave * 64;
    f32x16 t00 = fzero16(), t01 = fzero16(), t10 = fzero16(), t11 = fzero16();
    v00 = fzero16(); v01 = fzero16(); v10 = fzero16(); v11 = fzero16();
    const bf16* a0p = &sm.Xs[lm][0];
    const bf16* a1p = &sm.Xs[32 + lm][0];
    #pragma unroll 2
    for (int kc = 0; kc < 32; ++kc) {
      bf16x8 fb0 = pb0, fb1 = pb1, fc0 = pc0, fc1 = pc1;
      if (kc + 1 < 32) {
        const int nx = (kc + 1) * 512;
        pb0 = *(const bf16x8*)(mq0 + nx);
        pb1 = *(const bf16x8*)(mq1 + nx);
        pc0 = *(const bf16x8*)(vv0 + nx);
        pc1 = *(const bf16x8*)(vv1 + nx);
      }
      const int ko = kc * 16 + 8 * hk;
      bf16x8 fa0 = *(const bf16x8*)(a0p + ko);
      bf16x8 fa1 = *(const bf16x8*)(a1p + ko);
      t00 = MFMA32(fa0, fb0, t00); t01 = MFMA32(fa0, fb1, t01);
      t10 = MFMA32(fa1, fb0, t10); t11 = MFMA32(fa1, fb1, t11);
      v00 = MFMA32(fa0, fc0, v00); v01 = MFMA32(fa0, fc1, v01);
      v10 = MFMA32(fa1, fc0, v10); v11 = MFMA32(fa1, fc1, v11);
    }
    #pragma unroll
    for (int reg = 0; reg < 16; ++reg) {
      const int row = (reg & 3) + 8 * (reg >> 2) + 4 * hk;  // C/D layout [m74/m101]
      sm.u.T1s[row][n_base + lm]           = (bf16)t00[reg];
      sm.u.T1s[row][n_base + 32 + lm]      = (bf16)t01[reg];
      sm.u.T1s[32 + row][n_base + lm]      = (bf16)t10[reg];
      sm.u.T1s[32 + row][n_base + 32 + lm] = (bf16)t11[reg];
    }
  }
  __syncthreads();

  // ---- phase 2: waves 0-3: S = T1 * X^T (64x64, k=512); waves 4-7: sbias_j = X_j . w2
  if (wave < 4) {
    const int r = wave & 1, c = wave >> 1;
    f32x16 accS = fzero16();
    const bf16* ap = &sm.u.T1s[32 * r + lm][0];
    const bf16* bp = &sm.Xs[32 * c + lm][0];   // B[k=b][n=j] = X[j][b]: k-contiguous along Xs row
    #pragma unroll 4
    for (int k0 = 0; k0 < 512; k0 += 16) {
      const int ko = k0 + 8 * hk;
      bf16x8 fa = *(const bf16x8*)(ap + ko);
      bf16x8 fb = *(const bf16x8*)(bp + ko);
      accS = MFMA32(fa, fb, accS);
    }
    #pragma unroll
    for (int reg = 0; reg < 16; ++reg) {
      const int row = 32 * r + (reg & 3) + 8 * (reg >> 2) + 4 * hk;
      if (row < 52) sm.Ss[row][32 * c + lm] = accS[reg];
    }
  } else {
    const int t2 = tid - 256;
    const int j = t2 >> 2, part = t2 & 3;      // 4 threads per row, 128 chans each
    const bf16* xr = &sm.Xs[j][part * 128];
    const float* wr = ws2 + part * 128;
    float s = 0.f;
    #pragma unroll
    for (int t = 0; t < 16; ++t) {
      bf16x8 xv = *(const bf16x8*)(xr + 8 * t);
      float4 w0 = *(const float4*)(wr + 8 * t);
      float4 w1 = *(const float4*)(wr + 8 * t + 4);
      s += (float)xv[0] * w0.x + (float)xv[1] * w0.y + (float)xv[2] * w0.z + (float)xv[3] * w0.w
         + (float)xv[4] * w1.x + (float)xv[5] * w1.y + (float)xv[6] * w1.z + (float)xv[7] * w1.w;
    }
    s += __shfl_xor(s, 1);
    s += __shfl_xor(s, 2);
    if (part == 0) sm.sbias[j] = s;
  }
  __syncthreads();

  // ---- phase 3: wave-parallel masked softmax: 8 lanes per row, rows 0..48
  {
    const int srow = tid >> 3, sub = tid & 7;
    if (srow < 49) {
      float v[8];
      #pragma unroll
      for (int t = 0; t < 8; ++t) {
        const int col = sub + 8 * t;
        v[t] = (col < 49) ? (sm.Ss[srow][col] + sm.sbias[col]) : -1e30f;
      }
      float m = v[0];
      #pragma unroll
      for (int t = 1; t < 8; ++t) m = fmaxf(m, v[t]);
      m = fmaxf(m, __shfl_xor(m, 1, 64));
      m = fmaxf(m, __shfl_xor(m, 2, 64));
      m = fmaxf(m, __shfl_xor(m, 4, 64));
      float e[8]; float ssum = 0.f;
      #pragma unroll
      for (int t = 0; t < 8; ++t) {
        const int col = sub + 8 * t;
        e[t] = (col < 49) ? __expf(v[t] - m) : 0.f;
        ssum += e[t];
      }
      ssum += __shfl_xor(ssum, 1, 64);
      ssum += __shfl_xor(ssum, 2, 64);
      ssum += __shfl_xor(ssum, 4, 64);
      const float inv = 1.f / ssum;
      #pragma unroll
      for (int t = 0; t < 8; ++t)
        sm.Ps[srow][sub + 8 * t] = (bf16)(e[t] * inv);
    }
  }

  // ---- phase 4 (dump): V accs + bias -> Vt[chan][token]  (T1s reads finished at barrier above)
  {
    const int n_base = wave * 64;
    const float bv0 = bqkv[1024 + n_base + lm];
    const float bv1 = bqkv[1024 + n_base + 32 + lm];
    #pragma unroll
    for (int g = 0; g < 4; ++g) {
      const int t0 = 8 * g + 4 * hk;   // 4 consecutive token rows per reg-group
      bf16x4 p0, p1, p2, p3;
      #pragma unroll
      for (int j = 0; j < 4; ++j) {
        p0[j] = (bf16)(v00[4 * g + j] + bv0);
        p1[j] = (bf16)(v01[4 * g + j] + bv1);
        p2[j] = (bf16)(v10[4 * g + j] + bv0);
        p3[j] = (bf16)(v11[4 * g + j] + bv1);
      }
      *(bf16x4*)&sm.u.Vt[n_base + lm][t0]           = p0;
      *(bf16x4*)&sm.u.Vt[n_base + 32 + lm][t0]      = p1;
      *(bf16x4*)&sm.u.Vt[n_base + lm][32 + t0]      = p2;
      *(bf16x4*)&sm.u.Vt[n_base + 32 + lm][32 + t0] = p3;
    }
  }
  __syncthreads();

  // ---- phase 5: O = P * V (64x512, k=64), store f32 rows < 49
  {
    const int n_base = wave * 64;
    f32x16 a00 = fzero16(), a01 = fzero16(), a10 = fzero16(), a11 = fzero16();
    #pragma unroll
    for (int k0 = 0; k0 < 64; k0 += 16) {
      const int ko = k0 + 8 * hk;
      bf16x8 fa0 = *(const bf16x8*)&sm.Ps[lm][ko];
      bf16x8 fa1 = *(const bf16x8*)&sm.Ps[32 + lm][ko];
      bf16x8 fb0 = *(const bf16x8*)&sm.u.Vt[n_base + lm][ko];
      bf16x8 fb1 = *(const bf16x8*)&sm.u.Vt[n_base + 32 + lm][ko];
      a00 = MFMA32(fa0, fb0, a00); a01 = MFMA32(fa0, fb1, a01);
      a10 = MFMA32(fa1, fb0, a10); a11 = MFMA32(fa1, fb1, a11);
    }
    float* ow = out + (size_t)wid * 25088;
    const int c0_ = n_base + lm, c1_ = n_base + 32 + lm;
    #pragma unroll
    for (int reg = 0; reg < 16; ++reg) {
      const int row = (reg & 3) + 8 * (reg >> 2) + 4 * hk;
      if (row < 49) {
        ow[row * 512 + c0_] = a00[reg];
        ow[row * 512 + c1_] = a01[reg];
      }
      const int row1 = 32 + row;
      if (row1 < 49) {
        ow[row1 * 512 + c0_] = a10[reg];
        ow[row1 * 512 + c1_] = a11[reg];
      }
    }
  }
}

extern "C" void kernel_launch(void* const* d_in, const int* in_sizes, int n_in,
                              void* d_out, int out_size, void* d_ws, size_t ws_size,
                              hipStream_t stream) {
  const float* x    = (const float*)d_in[0];
  // d_in[1] (x_all) is unused by the reference
  const float* W    = (const float*)d_in[2];
  const float* bqkv = (const float*)d_in[3];
  float* out = (float*)d_out;

  bf16*  Mqk = (bf16*)d_ws;                                    // 512*512*2 = 512 KB (F-layout)
  bf16*  WvT = (bf16*)((char*)d_ws + 512 * 512 * 2);           // 512 KB (F-layout)
  float* w2  = (float*)((char*)d_ws + 2 * 512 * 512 * 2);      // 2 KB

  k_mqk<<<256, 256, 0, stream>>>(W, Mqk);
  k_wvt<<<64, 256, 0, stream>>>(W, WvT);
  k_w2 <<<512, 256, 0, stream>>>(W, bqkv, w2);
  k_attn<<<2048, 512, 0, stream>>>(x, bqkv, Mqk, WvT, w2, out);
}